// Round 3
// baseline (260.922 us; speedup 1.0000x reference)
//
#include <hip/hip_runtime.h>

typedef float f32x2 __attribute__((ext_vector_type(2)));
typedef float f32x4 __attribute__((ext_vector_type(4)));

// DPP quad_perm helpers: exchange within quads, pure VALU (no LDS, no barriers).
__device__ __forceinline__ float dpp_xor1(float v) {
  // quad_perm:[1,0,3,2] = 0xB1
  int r = __builtin_amdgcn_update_dpp(0, __builtin_bit_cast(int, v), 0xB1, 0xF, 0xF, true);
  return __builtin_bit_cast(float, r);
}
__device__ __forceinline__ float dpp_xor2(float v) {
  // quad_perm:[2,3,0,1] = 0x4E
  int r = __builtin_amdgcn_update_dpp(0, __builtin_bit_cast(int, v), 0x4E, 0xF, 0xF, true);
  return __builtin_bit_cast(float, r);
}

// i2-halves of W12 separated by 1576 floats (1576 % 32 = 8) so the only
// per-lane-varying LDS address bit lands on different banks.
#define W12_I2_STRIDE 1576

__global__ __launch_bounds__(256) void mnist_fused(
    const float* __restrict__ x,
    const float* __restrict__ W1, const float* __restrict__ b1,
    const float* __restrict__ W2, const float* __restrict__ b2,
    const float* __restrict__ W3, const float* __restrict__ b3,
    float* __restrict__ out, int nimg)
{
  // Composed layer-1+2 weights: W12[i2][j2*784 + p*16 + f2], 16 floats contiguous per (i2,j2,p).
  __shared__ __align__(16) float sW12[2 * W12_I2_STRIDE];
  __shared__ __align__(16) float sW3[10 * 64];
  __shared__ float sW1[16 * 49];
  __shared__ float sW2[16 * 64];
  __shared__ float sB12[16], sB3[10];

  const int tid = threadIdx.x;
  for (int i = tid; i < 784; i += 256)  sW1[i] = W1[i];
  for (int i = tid; i < 1024; i += 256) sW2[i] = W2[i];
  for (int i = tid; i < 640; i += 256)  sW3[i] = W3[i];
  if (tid < 10) sB3[tid] = b3[tid];
  __syncthreads();

  // Compose W12[f2][(i2,j2)][p] = sum_f W1[f][p] * W2[f2][(i2*2+j2)*16+f].
  for (int e = tid; e < 3136; e += 256) {
    int q = e / 784;                 // i2*2 + j2
    int r = e - q * 784;             // p*16 + f2
    int p = r >> 4, f2 = r & 15;
    float s = 0.f;
#pragma unroll
    for (int f = 0; f < 16; ++f)
      s = fmaf(sW1[f * 49 + p], sW2[f2 * 64 + q * 16 + f], s);
    sW12[(q >> 1) * W12_I2_STRIDE + (q & 1) * 784 + r] = s;
  }
  if (tid < 16) {                    // b12[f2] = b2[f2] + sum_k b1[k%16]*W2[f2][k]
    float s = b2[tid];
#pragma unroll
    for (int k = 0; k < 64; ++k)
      s = fmaf(b1[k & 15], sW2[tid * 64 + k], s);
    sB12[tid] = s;
  }
  __syncthreads();

  const int band = tid & 3;          // rows 7*band..7*band+6 ; i2 = J = band&1
  const int i2 = band & 1;
  const float* wbase = sW12 + i2 * W12_I2_STRIDE;

  f32x2 acc0[8], acc1[8];            // quadrant (I, J=0) and (I, J=1) partials
  // per-row compute: 28 pixels -> 16 features each via composed weights
  auto compute = [&](f32x4 (&rc)[7], int lr) {
    const float* wrow = wbase + lr * 112;          // p = lr*7 + pc
#pragma unroll
    for (int j2 = 0; j2 < 2; ++j2) {
#pragma unroll
      for (int pc = 0; pc < 7; ++pc) {
        const int woff = j2 * 784 + pc * 16;       // compile-time -> ds offset imm
        const f32x4* wp = (const f32x4*)(wrow + woff);
        f32x4 w0 = wp[0], w1 = wp[1], w2 = wp[2], w3 = wp[3];
        const int c0 = j2 * 7 + pc, c1 = c0 + 14;  // J=0 col, J=1 col (same weight)
        float v0 = rc[c0 >> 2][c0 & 3];
        float v1 = rc[c1 >> 2][c1 & 3];
        f32x2 v0v = { v0, v0 }, v1v = { v1, v1 };
        f32x2 wf[8] = { {w0.x,w0.y},{w0.z,w0.w},{w1.x,w1.y},{w1.z,w1.w},
                        {w2.x,w2.y},{w2.z,w2.w},{w3.x,w3.y},{w3.z,w3.w} };
#pragma unroll
        for (int fp = 0; fp < 8; ++fp) {
          acc0[fp] = __builtin_elementwise_fma(wf[fp], v0v, acc0[fp]);
          acc1[fp] = __builtin_elementwise_fma(wf[fp], v1v, acc1[fp]);
        }
      }
    }
  };

  const int nunit = (nimg * 4 + 255) >> 8;
  for (int unit = blockIdx.x; unit < nunit; unit += gridDim.x) {
    int g = (int)(unit * 256u + tid) >> 2;
    if (g >= nimg) g = nimg - 1;     // duplicate work, identical output: safe
    const f32x4* __restrict__ xq = (const f32x4*)x + (size_t)g * 196 + (size_t)band * 49;

#pragma unroll
    for (int fp = 0; fp < 8; ++fp) { acc0[fp] = f32x2{0.f,0.f}; acc1[fp] = f32x2{0.f,0.f}; }

    f32x4 A[7], Bv[7];
#pragma unroll
    for (int qq = 0; qq < 7; ++qq) A[qq] = xq[qq];            // row 0

#pragma unroll 1
    for (int lr = 0; lr < 6; lr += 2) {
      const f32x4* nx1 = xq + (lr + 1) * 7;
#pragma unroll
      for (int qq = 0; qq < 7; ++qq) Bv[qq] = nx1[qq];        // prefetch row lr+1
      compute(A, lr);
      const f32x4* nx2 = xq + (lr + 2) * 7;
#pragma unroll
      for (int qq = 0; qq < 7; ++qq) A[qq] = nx2[qq];         // prefetch row lr+2
      compute(Bv, lr + 1);
    }
    compute(A, 6);

    // Pair-combine row-halves (lane b + b^1) + bias + ReLU.
    float yr[16];
#pragma unroll
    for (int fp = 0; fp < 8; ++fp) {
      f32x2 own  = i2 ? acc1[fp] : acc0[fp];    // my quadrant (I, J=band&1)
      f32x2 send = i2 ? acc0[fp] : acc1[fp];    // partner's quadrant, my rows
      f32x2 nb = { dpp_xor1(send.x), dpp_xor1(send.y) };
      float y0 = own.x + nb.x + sB12[2 * fp];
      float y1 = own.y + nb.y + sB12[2 * fp + 1];
      yr[2 * fp]     = fmaxf(y0, 0.f);
      yr[2 * fp + 1] = fmaxf(y1, 0.f);
    }

    // Layer 3: lane b owns yflat block m = b*16..b*16+15; quad butterfly sum.
    float z[10];
#pragma unroll
    for (int o = 0; o < 10; ++o) {
      const f32x4* wr = (const f32x4*)(sW3 + o * 64 + band * 16);
      float s = 0.f;
#pragma unroll
      for (int t = 0; t < 4; ++t) {
        f32x4 w = wr[t];
        s = fmaf(w.x, yr[4 * t + 0], s);
        s = fmaf(w.y, yr[4 * t + 1], s);
        s = fmaf(w.z, yr[4 * t + 2], s);
        s = fmaf(w.w, yr[4 * t + 3], s);
      }
      s += dpp_xor1(s);
      s += dpp_xor2(s);
      z[o] = s + sB3[o];
    }

    // log_softmax (all indices compile-time -> registers, no scratch)
    float m = z[0];
#pragma unroll
    for (int o = 1; o < 10; ++o) m = fmaxf(m, z[o]);
    float ssum = 0.f;
#pragma unroll
    for (int o = 0; o < 10; ++o) ssum += __expf(z[o] - m);
    const float lse = m + __logf(ssum);

    // Vectorized, compile-time-indexed stores: 5 x f32x2 per image across bands 0..2.
    float* op = out + (size_t)g * 10;
    if (band == 0) {
      *(f32x2*)(op)     = f32x2{ z[0] - lse, z[1] - lse };
      *(f32x2*)(op + 2) = f32x2{ z[2] - lse, z[3] - lse };
    } else if (band == 1) {
      *(f32x2*)(op + 4) = f32x2{ z[4] - lse, z[5] - lse };
      *(f32x2*)(op + 6) = f32x2{ z[6] - lse, z[7] - lse };
    } else if (band == 2) {
      *(f32x2*)(op + 8) = f32x2{ z[8] - lse, z[9] - lse };
    }
  }
}

extern "C" void kernel_launch(void* const* d_in, const int* in_sizes, int n_in,
                              void* d_out, int out_size, void* d_ws, size_t ws_size,
                              hipStream_t stream) {
  const float* x  = (const float*)d_in[0];
  const float* W1 = (const float*)d_in[1];
  const float* b1 = (const float*)d_in[2];
  const float* W2 = (const float*)d_in[3];
  const float* b2 = (const float*)d_in[4];
  const float* W3 = (const float*)d_in[5];
  const float* b3 = (const float*)d_in[6];
  float* out = (float*)d_out;

  const int nimg = in_sizes[0] / 784;          // 131072
  const int nunit = (nimg * 4 + 255) / 256;    // 2048 work units
  const int blocks = nunit < 1024 ? nunit : 1024;  // grid-stride, ~4 blocks/CU
  mnist_fused<<<blocks, 256, 0, stream>>>(x, W1, b1, W2, b2, W3, b3, out, nimg);
}

// Round 5
// 87.350 us; speedup vs baseline: 2.9871x; 2.9871x over previous
//
#include <hip/hip_runtime.h>

typedef float f32x4 __attribute__((ext_vector_type(4)));
typedef short bf16x8 __attribute__((ext_vector_type(8)));

// LDS map (bytes):
//   [0, 29696)      per-wave x-stage: 4 waves x 16 rows x 464B (224 bf16 + pad)
//                   (setup reuses [0,7232) to stage raw W1/W2 for compose)
//   [29696, 37120)  W12 bf16: 16 rows (f2) x 464B  (232 bf16, 196 used)
//   [37120, 46336)  per-wave y: 4 waves x 16 rows (img) x 144B (64 bf16 + pad)
//   [46336, 46400)  b12 (16 f32)
#define XS 464
#define WOFF 29696
#define YOFF 37120
#define YS 144
#define BOFF 46336

// RNE float->bf16 on plain integer types (trivially copyable).
__device__ __forceinline__ unsigned short f2bf(float f) {
  unsigned u = __builtin_bit_cast(unsigned, f);
  u += 0x7FFFu + ((u >> 16) & 1u);
  return (unsigned short)(u >> 16);
}
__device__ __forceinline__ unsigned packbf2(float a, float b) {
  return (unsigned)f2bf(a) | ((unsigned)f2bf(b) << 16);
}

__global__ __launch_bounds__(256) void mnist_mfma(
    const float* __restrict__ x, const float* __restrict__ W1,
    const float* __restrict__ b1, const float* __restrict__ W2,
    const float* __restrict__ b2, const float* __restrict__ W3,
    const float* __restrict__ b3, float* __restrict__ out, int nimg)
{
  __shared__ __align__(16) char smem[46400];
  float* smemF = (float*)smem;
  const int tid = threadIdx.x;
  const int lane = tid & 63;
  const int waveid = tid >> 6;

  // ---- setup: stage raw W1/W2, compose W12 = W1∘W2 (bf16) + b12 ----------
  for (int i = tid; i < 784; i += 256) smemF[i] = W1[i];
  for (int i = tid; i < 1024; i += 256) smemF[784 + i] = W2[i];
  __syncthreads();

  unsigned short* w12b = (unsigned short*)(smem + WOFF);
  for (int e = tid; e < 3136; e += 256) {
    int f2 = e / 196, k = e - f2 * 196;
    int r14 = k / 14, c14 = k - r14 * 14;
    int pp = (r14 % 7) * 7 + (c14 % 7);          // within-patch pixel
    int q = (r14 / 7) * 2 + (c14 / 7);           // patch block i2*2+j2
    float s = 0.f;
#pragma unroll
    for (int f = 0; f < 16; ++f)
      s = fmaf(smemF[f * 49 + pp], smemF[784 + f2 * 64 + q * 16 + f], s);
    w12b[f2 * 232 + k] = f2bf(s);
  }
  for (int e = tid; e < 576; e += 256) {         // zero K-pad [196,232)
    int f2 = e / 36;
    w12b[f2 * 232 + 196 + (e - f2 * 36)] = 0;
  }
  if (tid < 16) {                                // b12 = b2 + b1-through-W2
    float s = b2[tid];
#pragma unroll
    for (int k = 0; k < 64; ++k)
      s = fmaf(b1[k & 15], smemF[784 + tid * 64 + k], s);
    smemF[BOFF / 4 + tid] = s;
  }
  __syncthreads();
  // no __syncthreads after this point: waves are fully independent.

  // ---- per-wave zero of x-stage K-pad (bytes [392,464) of each row) ------
  char* xw = smem + waveid * 7424;
#pragma unroll
  for (int j = 0; j < 5; ++j) {
    int idx = lane + 64 * j;
    if (idx < 288) {
      int row = idx / 18, d = idx - row * 18;
      *(unsigned*)(xw + row * XS + 392 + d * 4) = 0;
    }
  }

  // ---- preload fragments into registers ----------------------------------
  bf16x8 wfrag[7];                               // W12 B-frags: 28 VGPRs, whole K
#pragma unroll
  for (int i = 0; i < 7; ++i)
    wfrag[i] = *(const bf16x8*)(smem + WOFF + (lane & 15) * XS + (lane >> 4) * 16 + 64 * i);

  bf16x8 w3f[2];                                 // W3 A-frags (rows>=10 zero)
  {
    int o = lane & 15, kb = (lane >> 4) * 8;
#pragma unroll
    for (int mi = 0; mi < 2; ++mi) {
      float v[8];
#pragma unroll
      for (int j = 0; j < 8; ++j)
        v[j] = (o < 10) ? W3[o * 64 + kb + 32 * mi + j] : 0.f;
      unsigned t[4];
      t[0] = packbf2(v[0], v[1]); t[1] = packbf2(v[2], v[3]);
      t[2] = packbf2(v[4], v[5]); t[3] = packbf2(v[6], v[7]);
      w3f[mi] = __builtin_bit_cast(bf16x8, *(unsigned(*)[4])t);
    }
  }
  const float b12v = smemF[BOFF / 4 + (lane & 15)];
  float b3v[4];
#pragma unroll
  for (int r = 0; r < 4; ++r) {
    int o = (lane >> 4) * 4 + r;
    b3v[r] = (o < 10) ? b3[o] : 0.f;
  }

  // ---- staging addresses: raster float4 -> quadrant-stream bf16 pairs ----
  // group gi = lane + 64*it within a 4-image block (784 float4s).
  unsigned wa0[13]; unsigned strm = 0;
#pragma unroll
  for (int it = 0; it < 13; ++it) {
    int gi = lane + 64 * it;
    int im = gi / 196, rem = gi - im * 196;      // image, float4 within image
    int rr = rem / 7, t = rem - rr * 7;          // pixel row, 4-px group
    int c2 = 2 * t;                              // first bf16-pair column
    int J = c2 / 7, cq = c2 - 7 * J;
    int row = im * 4 + (rr / 14) * 2 + J;        // M-row = im*4 + (I*2+J)
    int kp = (rr % 14) * 7 + cq;                 // pair index in quadrant
    wa0[it] = waveid * 7424 + row * XS + kp * 4;
    if (t == 3) strm |= (1u << it);              // second pair crosses J-half
  }

  const unsigned xrd = waveid * 7424 + (lane & 15) * XS + (lane >> 4) * 16;
  const unsigned yw_base = YOFF + waveid * 2304 + (lane & 15) * 2;
  const unsigned yrd = YOFF + waveid * 2304 + (lane & 15) * YS + (lane >> 4) * 16;

  const int NU = nimg >> 4;                      // 16-image units
  const int WST = (int)(gridDim.x << 2);         // total waves
  const int w0 = (int)(blockIdx.x << 2) + waveid;
  const int ng4 = nimg >> 2;                     // 4-image groups

  f32x4 cur[13];
  const f32x4* __restrict__ xq0 = (const f32x4*)x;
  auto issue4 = [&](int g4) {                    // 13 coalesced dwordx4 loads
    const f32x4* p = xq0 + (size_t)g4 * 784;
#pragma unroll
    for (int it = 0; it < 12; ++it) cur[it] = p[lane + 64 * it];
    if (lane < 16) cur[12] = p[768 + lane];
  };

  if (w0 < NU) issue4(w0 * 4);

  for (int u = w0; u < NU; u += WST) {
#pragma unroll 1
    for (int sb = 0; sb < 4; ++sb) {
      // stage cur -> LDS (compiler inserts the vmcnt wait on cur)
#pragma unroll
      for (int it = 0; it < 13; ++it) {
        if (it == 12 && lane >= 16) continue;
        f32x4 v = cur[it];
        unsigned a0 = wa0[it];
        unsigned d = ((strm >> it) & 1) ? 440u : 4u;
        *(unsigned*)(smem + a0) = packbf2(v.x, v.y);
        *(unsigned*)(smem + a0 + d) = packbf2(v.z, v.w);
      }
      // prefetch next 4-image group (1 sub-batch deep)
      int ng = (sb < 3) ? (u * 4 + sb + 1) : ((u + WST) * 4);
      if (ng < ng4) issue4(ng);
      // GEMM1: y(16 rows x 16 f2) = P(16 x 224) * W12(224 x 16)
      f32x4 acc = {0.f, 0.f, 0.f, 0.f};
#pragma unroll
      for (int i = 0; i < 7; ++i) {
        bf16x8 a = *(const bf16x8*)(smem + xrd + 64 * i);
        acc = __builtin_amdgcn_mfma_f32_16x16x32_bf16(a, wfrag[i], acc, 0, 0, 0);
      }
      // bias + ReLU + bf16 -> y LDS  (D: img=lane>>4, q=r, f2=lane&15)
      unsigned yb = yw_base + (unsigned)(sb * 4 + (lane >> 4)) * YS;
#pragma unroll
      for (int r = 0; r < 4; ++r) {
        float yv = fmaxf(acc[r] + b12v, 0.f);
        *(unsigned short*)(smem + yb + r * 32) = f2bf(yv);
      }
    }
    // GEMM2: z^T(16 o x 16 img) = W3(16x64) * y^T(64x16) over the unit
    f32x4 z4 = {0.f, 0.f, 0.f, 0.f};
#pragma unroll
    for (int mi = 0; mi < 2; ++mi) {
      bf16x8 bfr = *(const bf16x8*)(smem + yrd + 64 * mi);
      z4 = __builtin_amdgcn_mfma_f32_16x16x32_bf16(w3f[mi], bfr, z4, 0, 0, 0);
    }
    // log_softmax over o = (lane>>4)*4 + r (10 valid), img = lane&15
    float zv[4], mval = -3.0e38f;
#pragma unroll
    for (int r = 0; r < 4; ++r) {
      zv[r] = z4[r] + b3v[r];
      bool valid = ((lane >> 4) * 4 + r) < 10;
      mval = fmaxf(mval, valid ? zv[r] : -3.0e38f);
    }
    mval = fmaxf(mval, __shfl_xor(mval, 16, 64));
    mval = fmaxf(mval, __shfl_xor(mval, 32, 64));
    float ssum = 0.f;
#pragma unroll
    for (int r = 0; r < 4; ++r) {
      bool valid = ((lane >> 4) * 4 + r) < 10;
      ssum += valid ? __expf(zv[r] - mval) : 0.f;
    }
    ssum += __shfl_xor(ssum, 16, 64);
    ssum += __shfl_xor(ssum, 32, 64);
    const float lse = mval + __logf(ssum);
    float* op = out + (size_t)(u * 16 + (lane & 15)) * 10;
#pragma unroll
    for (int r = 0; r < 4; ++r) {
      int o = (lane >> 4) * 4 + r;
      if (o < 10) op[o] = zv[r] - lse;
    }
  }
}

extern "C" void kernel_launch(void* const* d_in, const int* in_sizes, int n_in,
                              void* d_out, int out_size, void* d_ws, size_t ws_size,
                              hipStream_t stream) {
  const float* x  = (const float*)d_in[0];
  const float* W1 = (const float*)d_in[1];
  const float* b1 = (const float*)d_in[2];
  const float* W2 = (const float*)d_in[3];
  const float* b2 = (const float*)d_in[4];
  const float* W3 = (const float*)d_in[5];
  const float* b3 = (const float*)d_in[6];
  float* out = (float*)d_out;

  const int nimg = in_sizes[0] / 784;  // 131072
  // 512 blocks = 2048 waves -> exactly 4 units/wave at 131072 images.
  // 2 blocks/CU at 46.4 KB LDS.
  mnist_mfma<<<512, 256, 0, stream>>>(x, W1, b1, W2, b2, W3, b3, out, nimg);
}

// Round 6
// 86.529 us; speedup vs baseline: 3.0154x; 1.0095x over previous
//
#include <hip/hip_runtime.h>

typedef float f32x4 __attribute__((ext_vector_type(4)));
typedef short bf16x8 __attribute__((ext_vector_type(8)));

// LDS map (bytes):
//   [0, 29696)      per-wave x-stage: 4 waves x 16 rows x 464B (224 bf16 + pad)
//                   (setup reuses [0,7232) to stage raw W1/W2 for compose)
//   [29696, 37120)  W12 bf16 (setup only; preloaded to regs, then DEAD)
//   [29696, 38912)  per-wave y (ALIASES W12 after preload): 4 x 16 x 144B
//   [38912, 38976)  b12 (16 f32)
// Total 38976 B -> 4 blocks/CU (155.9 KB of 160 KB).
#define XS 464
#define WOFF 29696
#define YOFF 29696
#define YS 144
#define BOFF 38912

// RNE float->bf16 on plain integer types (trivially copyable).
__device__ __forceinline__ unsigned short f2bf(float f) {
  unsigned u = __builtin_bit_cast(unsigned, f);
  u += 0x7FFFu + ((u >> 16) & 1u);
  return (unsigned short)(u >> 16);
}
__device__ __forceinline__ unsigned packbf2(float a, float b) {
  return (unsigned)f2bf(a) | ((unsigned)f2bf(b) << 16);
}

__global__ __launch_bounds__(256, 2) void mnist_mfma(
    const float* __restrict__ x, const float* __restrict__ W1,
    const float* __restrict__ b1, const float* __restrict__ W2,
    const float* __restrict__ b2, const float* __restrict__ W3,
    const float* __restrict__ b3, float* __restrict__ out, int nimg)
{
  __shared__ __align__(16) char smem[38976];
  float* smemF = (float*)smem;
  const int tid = threadIdx.x;
  const int lane = tid & 63;
  const int waveid = tid >> 6;

  // ---- setup: stage raw W1/W2, compose W12 = W1∘W2 (bf16) + b12 ----------
  for (int i = tid; i < 784; i += 256) smemF[i] = W1[i];
  for (int i = tid; i < 1024; i += 256) smemF[784 + i] = W2[i];
  __syncthreads();

  unsigned short* w12b = (unsigned short*)(smem + WOFF);
  for (int e = tid; e < 3136; e += 256) {
    int f2 = e / 196, k = e - f2 * 196;
    int r14 = k / 14, c14 = k - r14 * 14;
    int pp = (r14 % 7) * 7 + (c14 % 7);          // within-patch pixel
    int q = (r14 / 7) * 2 + (c14 / 7);           // patch block i2*2+j2
    float s = 0.f;
#pragma unroll
    for (int f = 0; f < 16; ++f)
      s = fmaf(smemF[f * 49 + pp], smemF[784 + f2 * 64 + q * 16 + f], s);
    w12b[f2 * 232 + k] = f2bf(s);
  }
  for (int e = tid; e < 576; e += 256) {         // zero K-pad [196,232)
    int f2 = e / 36;
    w12b[f2 * 232 + 196 + (e - f2 * 36)] = 0;
  }
  if (tid < 16) {                                // b12 = b2 + b1-through-W2
    float s = b2[tid];
#pragma unroll
    for (int k = 0; k < 64; ++k)
      s = fmaf(b1[k & 15], smemF[784 + tid * 64 + k], s);
    smemF[BOFF / 4 + tid] = s;
  }
  __syncthreads();

  // ---- preload fragments into registers ----------------------------------
  bf16x8 wfrag[7];                               // W12 B-frags: 28 VGPRs, whole K
#pragma unroll
  for (int i = 0; i < 7; ++i)
    wfrag[i] = *(const bf16x8*)(smem + WOFF + (lane & 15) * XS + (lane >> 4) * 16 + 64 * i);

  bf16x8 w3f[2];                                 // W3 A-frags (rows>=10 zero)
  {
    int o = lane & 15, kb = (lane >> 4) * 8;
#pragma unroll
    for (int mi = 0; mi < 2; ++mi) {
      float v[8];
#pragma unroll
      for (int j = 0; j < 8; ++j)
        v[j] = (o < 10) ? W3[o * 64 + kb + 32 * mi + j] : 0.f;
      unsigned t[4];
      t[0] = packbf2(v[0], v[1]); t[1] = packbf2(v[2], v[3]);
      t[2] = packbf2(v[4], v[5]); t[3] = packbf2(v[6], v[7]);
      w3f[mi] = __builtin_bit_cast(bf16x8, *(unsigned(*)[4])t);
    }
  }
  const float b12v = smemF[BOFF / 4 + (lane & 15)];
  float b3v[4];
#pragma unroll
  for (int r = 0; r < 4; ++r) {
    int o = (lane >> 4) * 4 + r;
    b3v[r] = (o < 10) ? b3[o] : 0.f;
  }
  // All waves have W12 in registers; y-region may now alias it.
  __syncthreads();

  // ---- per-wave zero of x-stage K-pad (bytes [392,464) of each row) ------
  char* xw = smem + waveid * 7424;
#pragma unroll
  for (int j = 0; j < 5; ++j) {
    int idx = lane + 64 * j;
    if (idx < 288) {
      int row = idx / 18, d = idx - row * 18;
      *(unsigned*)(xw + row * XS + 392 + d * 4) = 0;
    }
  }

  // ---- staging addresses: raster float4 -> quadrant-stream bf16 pairs ----
  unsigned wa0[13]; unsigned strm = 0;
#pragma unroll
  for (int it = 0; it < 13; ++it) {
    int gi = lane + 64 * it;
    int im = gi / 196, rem = gi - im * 196;      // image, float4 within image
    int rr = rem / 7, t = rem - rr * 7;          // pixel row, 4-px group
    int c2 = 2 * t;                              // first bf16-pair column
    int J = c2 / 7, cq = c2 - 7 * J;
    int row = im * 4 + (rr / 14) * 2 + J;        // M-row = im*4 + (I*2+J)
    int kp = (rr % 14) * 7 + cq;                 // pair index in quadrant
    wa0[it] = waveid * 7424 + row * XS + kp * 4;
    if (t == 3) strm |= (1u << it);              // second pair crosses J-half
  }

  const unsigned xrd = waveid * 7424 + (lane & 15) * XS + (lane >> 4) * 16;
  const unsigned yw_base = YOFF + waveid * 2304 + (lane & 15) * 2;
  const unsigned yrd = YOFF + waveid * 2304 + (lane & 15) * YS + (lane >> 4) * 16;

  const int NU = nimg >> 4;                      // 16-image units
  const int WST = (int)(gridDim.x << 2);         // total waves
  const int w0 = (int)(blockIdx.x << 2) + waveid;
  const int ng4 = nimg >> 2;                     // 4-image groups

  f32x4 cur[13];
  const f32x4* __restrict__ xq0 = (const f32x4*)x;
  auto issue4 = [&](int g4) {                    // 13 coalesced dwordx4 loads
    const f32x4* p = xq0 + (size_t)g4 * 784;
#pragma unroll
    for (int it = 0; it < 12; ++it) cur[it] = p[lane + 64 * it];
    if (lane < 16) cur[12] = p[768 + lane];
  };

  if (w0 < NU) issue4(w0 * 4);

  for (int u = w0; u < NU; u += WST) {
#pragma unroll 1
    for (int sb = 0; sb < 4; ++sb) {
      // stage cur -> LDS (compiler inserts the vmcnt wait on cur)
#pragma unroll
      for (int it = 0; it < 13; ++it) {
        if (it == 12 && lane >= 16) continue;
        f32x4 v = cur[it];
        unsigned a0 = wa0[it];
        unsigned d = ((strm >> it) & 1) ? 440u : 4u;
        *(unsigned*)(smem + a0) = packbf2(v.x, v.y);
        *(unsigned*)(smem + a0 + d) = packbf2(v.z, v.w);
      }
      // prefetch next 4-image group (1 sub-batch deep)
      int ng = (sb < 3) ? (u * 4 + sb + 1) : ((u + WST) * 4);
      if (ng < ng4) issue4(ng);
      // GEMM1: y(16 rows x 16 f2) = P(16 x 224) * W12(224 x 16)
      f32x4 acc = {0.f, 0.f, 0.f, 0.f};
#pragma unroll
      for (int i = 0; i < 7; ++i) {
        bf16x8 a = *(const bf16x8*)(smem + xrd + 64 * i);
        acc = __builtin_amdgcn_mfma_f32_16x16x32_bf16(a, wfrag[i], acc, 0, 0, 0);
      }
      // bias + ReLU + bf16 -> y LDS  (D: img=lane>>4, q=r, f2=lane&15)
      unsigned yb = yw_base + (unsigned)(sb * 4 + (lane >> 4)) * YS;
#pragma unroll
      for (int r = 0; r < 4; ++r) {
        float yv = fmaxf(acc[r] + b12v, 0.f);
        *(unsigned short*)(smem + yb + r * 32) = f2bf(yv);
      }
    }
    // GEMM2: z^T(16 o x 16 img) = W3(16x64) * y^T(64x16) over the unit
    f32x4 z4 = {0.f, 0.f, 0.f, 0.f};
#pragma unroll
    for (int mi = 0; mi < 2; ++mi) {
      bf16x8 bfr = *(const bf16x8*)(smem + yrd + 64 * mi);
      z4 = __builtin_amdgcn_mfma_f32_16x16x32_bf16(w3f[mi], bfr, z4, 0, 0, 0);
    }
    // log_softmax over o = (lane>>4)*4 + r (10 valid), img = lane&15
    float zv[4], mval = -3.0e38f;
#pragma unroll
    for (int r = 0; r < 4; ++r) {
      zv[r] = z4[r] + b3v[r];
      bool valid = ((lane >> 4) * 4 + r) < 10;
      mval = fmaxf(mval, valid ? zv[r] : -3.0e38f);
    }
    mval = fmaxf(mval, __shfl_xor(mval, 16, 64));
    mval = fmaxf(mval, __shfl_xor(mval, 32, 64));
    float ssum = 0.f;
#pragma unroll
    for (int r = 0; r < 4; ++r) {
      bool valid = ((lane >> 4) * 4 + r) < 10;
      ssum += valid ? __expf(zv[r] - mval) : 0.f;
    }
    ssum += __shfl_xor(ssum, 16, 64);
    ssum += __shfl_xor(ssum, 32, 64);
    const float lse = mval + __logf(ssum);
    float* op = out + (size_t)(u * 16 + (lane & 15)) * 10;
#pragma unroll
    for (int r = 0; r < 4; ++r) {
      int o = (lane >> 4) * 4 + r;
      if (o < 10) op[o] = zv[r] - lse;
    }
  }
}

extern "C" void kernel_launch(void* const* d_in, const int* in_sizes, int n_in,
                              void* d_out, int out_size, void* d_ws, size_t ws_size,
                              hipStream_t stream) {
  const float* x  = (const float*)d_in[0];
  const float* W1 = (const float*)d_in[1];
  const float* b1 = (const float*)d_in[2];
  const float* W2 = (const float*)d_in[3];
  const float* b2 = (const float*)d_in[4];
  const float* W3 = (const float*)d_in[5];
  const float* b3 = (const float*)d_in[6];
  float* out = (float*)d_out;

  const int nimg = in_sizes[0] / 784;  // 131072
  // 1024 blocks = 4096 waves -> exactly 2 units/wave; 4 blocks/CU at 39 KB LDS.
  mnist_mfma<<<1024, 256, 0, stream>>>(x, W1, b1, W2, b2, W3, b3, out, nimg);
}